// Round 3
// baseline (173.624 us; speedup 1.0000x reference)
//
#include <hip/hip_runtime.h>

#define C2 0.17677669529663687f  // 1/(4*sqrt(2))

typedef __attribute__((ext_vector_type(8))) short short8;
typedef __attribute__((ext_vector_type(8))) unsigned short ushort8;
typedef __attribute__((ext_vector_type(4))) float f32x4;

// fp32 -> bf16 round-to-nearest-even
__device__ __forceinline__ unsigned short f2bf(float x) {
    union { float f; unsigned u; } v; v.f = x;
    unsigned r = v.u + 0x7fffu + ((v.u >> 16) & 1u);
    return (unsigned short)(r >> 16);
}
__device__ __forceinline__ float bf2f(unsigned short u) {
    union { unsigned u; float f; } v; v.u = ((unsigned)u) << 16;
    return v.f;
}

// ---------------- device-scope grid barrier (generation counter; round-1 verified) ----------------
__device__ __forceinline__ void grid_sync(int* bar, int nblk) {
    __syncthreads();
    if (threadIdx.x == 0) {
        __threadfence();   // release: make this block's global writes visible cross-XCD
        int gen = __hip_atomic_load(&bar[1], __ATOMIC_RELAXED, __HIP_MEMORY_SCOPE_AGENT);
        int arr = __hip_atomic_fetch_add(&bar[0], 1, __ATOMIC_ACQ_REL, __HIP_MEMORY_SCOPE_AGENT);
        if (arr == nblk - 1) {
            __hip_atomic_store(&bar[0], 0, __ATOMIC_RELAXED, __HIP_MEMORY_SCOPE_AGENT);
            __hip_atomic_store(&bar[1], gen + 1, __ATOMIC_RELEASE, __HIP_MEMORY_SCOPE_AGENT);
        } else {
            int cur;
            do {
                __builtin_amdgcn_s_sleep(2);
                cur = __hip_atomic_load(&bar[1], __ATOMIC_ACQUIRE, __HIP_MEMORY_SCOPE_AGENT);
            } while (cur == gen);
        }
        __threadfence();
    }
    __syncthreads();
}

// ---------------- in-block split-K MFMA GEMM (unchanged, verified) ----------------
__device__ __forceinline__ void gemm_inblk_splitk(
    const float* __restrict__ A, const float* __restrict__ W,
    float* __restrict__ out, int row0, int n0, int outcol0, int ldw, int outld)
{
    __shared__ unsigned short Al[2][2][64][40];   // [group][buf]
    __shared__ unsigned short Bl[2][2][64][40];
    __shared__ float red[64][65];
    const int tid = threadIdx.x;            // 0..511
    const int g = tid >> 8;                 // K-group
    const int t = tid & 255;
    const int lane = t & 63, wave4 = t >> 6;
    const int wm = wave4 & 1, wn = wave4 >> 1;
    const int quad = lane >> 4, lr = lane & 15;
    const int k0base = g * 384;

    f32x4 acc[2][2] = {{{0.f,0.f,0.f,0.f},{0.f,0.f,0.f,0.f}},
                       {{0.f,0.f,0.f,0.f},{0.f,0.f,0.f,0.f}}};

    float4 ra[2], rb[2];
    #pragma unroll
    for (int l = 0; l < 2; ++l) {
        int idx = t + l * 256;
        ra[l] = *(const float4*)&A[(size_t)(row0 + (idx >> 3)) * 768 + k0base + (idx & 7) * 4];
        rb[l] = *(const float4*)&W[(size_t)(k0base + (idx >> 4)) * ldw + n0 + (idx & 15) * 4];
    }
    #pragma unroll
    for (int l = 0; l < 2; ++l) {
        int idx = t + l * 256;
        *(ushort4*)&Al[g][0][idx >> 3][(idx & 7) * 4] =
            make_ushort4(f2bf(ra[l].x), f2bf(ra[l].y), f2bf(ra[l].z), f2bf(ra[l].w));
        int kr = idx >> 4, nq = (idx & 15) * 4;
        int col = (((kr >> 3) ^ ((idx & 15) >> 2)) << 3) | (kr & 7);
        Bl[g][0][nq + 0][col] = f2bf(rb[l].x);
        Bl[g][0][nq + 1][col] = f2bf(rb[l].y);
        Bl[g][0][nq + 2][col] = f2bf(rb[l].z);
        Bl[g][0][nq + 3][col] = f2bf(rb[l].w);
    }
    __syncthreads();

    const int ITER = 12;   // 384 / 32
    #pragma unroll
    for (int i = 0; i < ITER; ++i) {
        const int cur = i & 1, nxt = cur ^ 1;
        float4 na[2], nb[2];
        if (i + 1 < ITER) {
            int kn = k0base + (i + 1) * 32;
            #pragma unroll
            for (int l = 0; l < 2; ++l) {
                int idx = t + l * 256;
                na[l] = *(const float4*)&A[(size_t)(row0 + (idx >> 3)) * 768 + kn + (idx & 7) * 4];
                nb[l] = *(const float4*)&W[(size_t)(kn + (idx >> 4)) * ldw + n0 + (idx & 15) * 4];
            }
        }
        short8 af[2], bfr[2];
        #pragma unroll
        for (int mi = 0; mi < 2; ++mi)
            af[mi] = *(const short8*)&Al[g][cur][wm * 32 + mi * 16 + lr][quad << 3];
        #pragma unroll
        for (int ni = 0; ni < 2; ++ni) {
            int csw = quad ^ ((wn * 2 + ni) & 3);
            bfr[ni] = *(const short8*)&Bl[g][cur][wn * 32 + ni * 16 + lr][csw << 3];
        }
        #pragma unroll
        for (int mi = 0; mi < 2; ++mi)
            #pragma unroll
            for (int ni = 0; ni < 2; ++ni)
                acc[mi][ni] = __builtin_amdgcn_mfma_f32_16x16x32_bf16(af[mi], bfr[ni], acc[mi][ni], 0, 0, 0);
        if (i + 1 < ITER) {
            #pragma unroll
            for (int l = 0; l < 2; ++l) {
                int idx = t + l * 256;
                *(ushort4*)&Al[g][nxt][idx >> 3][(idx & 7) * 4] =
                    make_ushort4(f2bf(na[l].x), f2bf(na[l].y), f2bf(na[l].z), f2bf(na[l].w));
                int kr = idx >> 4, nq = (idx & 15) * 4;
                int col = (((kr >> 3) ^ ((idx & 15) >> 2)) << 3) | (kr & 7);
                Bl[g][nxt][nq + 0][col] = f2bf(nb[l].x);
                Bl[g][nxt][nq + 1][col] = f2bf(nb[l].y);
                Bl[g][nxt][nq + 2][col] = f2bf(nb[l].z);
                Bl[g][nxt][nq + 3][col] = f2bf(nb[l].w);
            }
        }
        __syncthreads();
    }
    if (g == 1) {
        #pragma unroll
        for (int mi = 0; mi < 2; ++mi)
            #pragma unroll
            for (int ni = 0; ni < 2; ++ni)
                #pragma unroll
                for (int r = 0; r < 4; ++r)
                    red[wm * 32 + mi * 16 + quad * 4 + r][wn * 32 + ni * 16 + lr] = acc[mi][ni][r];
    }
    __syncthreads();
    if (g == 0) {
        #pragma unroll
        for (int mi = 0; mi < 2; ++mi)
            #pragma unroll
            for (int ni = 0; ni < 2; ++ni)
                #pragma unroll
                for (int r = 0; r < 4; ++r) {
                    int rr = wm * 32 + mi * 16 + quad * 4 + r;
                    int cc = wn * 32 + ni * 16 + lr;
                    out[(size_t)(row0 + rr) * outld + outcol0 + cc] = acc[mi][ni][r] + red[rr][cc];
                }
    }
}

// qkv: hidden(1024x768) @ [Wq|Wk|Wv] -> qkv(1024x1152). grid (18,16) x 512.
// Block (0,0) also zero-inits the grid-barrier state for the fused kernel (stream-ordered).
__global__ __launch_bounds__(512) void gemm_qkv_mfma(
    const float* __restrict__ H, const float* __restrict__ Wq,
    const float* __restrict__ Wk, const float* __restrict__ Wv,
    float* __restrict__ out, int* __restrict__ bar)
{
    if (blockIdx.x == 0 && blockIdx.y == 0 && threadIdx.x == 0) { bar[0] = 0; bar[1] = 0; }
    const int nt = blockIdx.x, mt = blockIdx.y;
    const float* W; int ldw, n0;
    if (nt < 3)      { W = Wq; ldw = 192; n0 = nt * 64; }
    else if (nt < 6) { W = Wk; ldw = 192; n0 = (nt - 3) * 64; }
    else             { W = Wv; ldw = 768; n0 = (nt - 6) * 64; }
    gemm_inblk_splitk(H, W, out, mt * 64, n0, nt * 64, ldw, 1152);
}

// wo: y(1024x768) @ Wo(768x768) -> out(1024x768). grid (12,16) x 512
__global__ __launch_bounds__(512) void gemm_wo_mfma(
    const float* __restrict__ Y, const float* __restrict__ Wo, float* __restrict__ out)
{
    const int nt = blockIdx.x, mt = blockIdx.y;
    gemm_inblk_splitk(Y, Wo, out, mt * 64, nt * 64, nt * 64, 768, 768);
}

// ---------------- fused attention: state -> scan -> out (192 blocks x 512 thr, 2 grid barriers) ----
struct StateSm {
    float Kc[64][17];
    unsigned short Pk[320][72];
    unsigned short Vt[80][72];
};
struct OutSm {
    float Qc[64][17];
    unsigned short Aq[64][40];
    unsigned short Kb[64][40];
    unsigned short Pq[64][360];
    unsigned short Vt[64][72];
    float zl[288];
    float dpart[12][64];
};
union __align__(16) AttnSm { StateSm a; OutSm c; };   // 74,112 B -> 2 blocks/CU capacity; 192 blocks co-resident

__global__ __launch_bounds__(512) void fused_attn(
    const float* __restrict__ qkv, unsigned short* __restrict__ St, float* __restrict__ zb,
    float* __restrict__ y, int* __restrict__ bar)
{
    __shared__ AttnSm sm;
    const int b = blockIdx.x;
    const int c = b & 15, h = b >> 4;
    const int tid = threadIdx.x;
    const int lane = tid & 63, wave = tid >> 6;       // 8 waves
    const int quad = lane >> 4, lr = lane & 15;

    // ---------- Phase A: per-chunk state S_T (bf16, zero-padded cols 273..287) + z ----------
    {
        if (tid < 256) {
            int s = tid >> 2, f4 = (tid & 3) * 4;
            float4 kv = *(const float4*)&qkv[(size_t)(c * 64 + s) * 1152 + 192 + h * 16 + f4];
            sm.a.Kc[s][f4 + 0] = kv.x; sm.a.Kc[s][f4 + 1] = kv.y;
            sm.a.Kc[s][f4 + 2] = kv.z; sm.a.Kc[s][f4 + 3] = kv.w;
        }
        #pragma unroll
        for (int l = 0; l < 2; ++l) {
            int idx = tid + l * 512;
            int s = idx >> 4, d4 = (idx & 15) * 4;
            float4 vv = *(const float4*)&qkv[(size_t)(c * 64 + s) * 1152 + 384 + h * 64 + d4];
            sm.a.Vt[d4 + 0][s] = f2bf(vv.x);
            sm.a.Vt[d4 + 1][s] = f2bf(vv.y);
            sm.a.Vt[d4 + 2][s] = f2bf(vv.z);
            sm.a.Vt[d4 + 3][s] = f2bf(vv.w);
        }
        for (int idx = tid; idx < 16 * 72; idx += 512) {
            int rr = 64 + idx / 72, ss = idx % 72;
            sm.a.Vt[rr][ss] = (rr == 64 && ss < 64) ? (unsigned short)0x3F80 : (unsigned short)0;
        }
        __syncthreads();
        for (int idx = tid; idx < 2880; idx += 512) {
            int n = idx / 9, s8 = (idx % 9) * 8;
            short8 v8;
            #pragma unroll
            for (int tt = 0; tt < 8; ++tt) {
                int s = s8 + tt;
                float ph = 0.f;
                if (s < 64 && n < 273) {
                    if (n == 0) ph = 1.f;
                    else if (n < 17) ph = sm.a.Kc[s][n - 1] * 0.5f;
                    else { int m = n - 17; ph = sm.a.Kc[s][m >> 4] * sm.a.Kc[s][m & 15] * C2; }
                }
                v8[tt] = (short)f2bf(ph);
            }
            *(short8*)&sm.a.Pk[n][s8] = v8;
        }
        __syncthreads();

        // 20 feature n-tiles over 8 waves: wave w owns tiles w, w+8, w+16(<20)  [round-1 verified]
        f32x4 acc[5][3];
        #pragma unroll
        for (int mt = 0; mt < 5; ++mt)
            #pragma unroll
            for (int nt = 0; nt < 3; ++nt) acc[mt][nt] = (f32x4){0.f, 0.f, 0.f, 0.f};
        #pragma unroll
        for (int ks = 0; ks < 2; ++ks) {
            short8 af[5], bfr[3];
            #pragma unroll
            for (int mt = 0; mt < 5; ++mt)
                af[mt] = *(const short8*)&sm.a.Vt[mt * 16 + lr][ks * 32 + quad * 8];
            #pragma unroll
            for (int nt = 0; nt < 3; ++nt)
                if (wave + 8 * nt < 20)
                    bfr[nt] = *(const short8*)&sm.a.Pk[(wave + 8 * nt) * 16 + lr][ks * 32 + quad * 8];
            #pragma unroll
            for (int mt = 0; mt < 5; ++mt)
                #pragma unroll
                for (int nt = 0; nt < 3; ++nt)
                    if (wave + 8 * nt < 20)
                        acc[mt][nt] = __builtin_amdgcn_mfma_f32_16x16x32_bf16(af[mt], bfr[nt], acc[mt][nt], 0, 0, 0);
        }
        unsigned short* Sbt = St + (size_t)(h * 16 + c) * 18432;
        float* zp = zb + (h * 16 + c) * 273;
        #pragma unroll
        for (int nt = 0; nt < 3; ++nt) {
            int tile = wave + 8 * nt;
            if (tile < 20) {
                int n = tile * 16 + lr;
                if (n < 288) {
                    #pragma unroll
                    for (int mt = 0; mt < 4; ++mt)
                        #pragma unroll
                        for (int r = 0; r < 4; ++r)
                            Sbt[(mt * 16 + quad * 4 + r) * 288 + n] =
                                (n < 273) ? f2bf(acc[mt][nt][r]) : (unsigned short)0;
                    if (quad == 0 && n < 273) zp[n] = acc[4][nt][0];
                }
            }
        }
    }
    grid_sync(bar, 192);

    // ---------- Phase B: exclusive prefix over 16 chunks (batched loads; round-2 verified) ----------
    {
        int gid = b * 512 + tid;
        const int NV = 12 * 64 * 36;
        if (gid < NV) {
            int hh = gid / (64 * 36), rem = gid % (64 * 36);
            int d = rem / 36, nb = rem % 36;
            unsigned short* p = St + (size_t)hh * 16 * 18432 + d * 288 + nb * 8;
            ushort8 v[16];
            #pragma unroll
            for (int cc = 0; cc < 16; ++cc) v[cc] = *(const ushort8*)(p + (size_t)cc * 18432);
            float run[8] = {0.f,0.f,0.f,0.f,0.f,0.f,0.f,0.f};
            #pragma unroll
            for (int cc = 0; cc < 16; ++cc) {
                ushort8 w;
                #pragma unroll
                for (int j = 0; j < 8; ++j) {
                    w[j] = f2bf(run[j]);
                    run[j] += bf2f(v[cc][j]);
                }
                *(ushort8*)(p + (size_t)cc * 18432) = w;
            }
        } else if (gid < NV + 12 * 273) {
            int e2 = gid - NV, hh = e2 / 273, n = e2 % 273;
            float* p = zb + hh * 16 * 273 + n;
            float v[16];
            #pragma unroll
            for (int cc = 0; cc < 16; ++cc) v[cc] = p[cc * 273];
            float run = 0.f;
            #pragma unroll
            for (int cc = 0; cc < 16; ++cc) { p[cc * 273] = run; run += v[cc]; }
        }
    }
    grid_sync(bar, 192);

    // ---------- Phase C: per-chunk output, 8-wave (2x4 wave grid, 32x16 tiles/wave) ----------
    {
        const int wm = wave & 1, wn = wave >> 1;       // wn in 0..3 (16-col quarters)

        // state B-fragments from global (post-scan): issue first, used only in final GEMM
        const unsigned short* Sgt = St + (size_t)(h * 16 + c) * 18432;
        short8 sfr[9];
        #pragma unroll
        for (int ks = 0; ks < 9; ++ks)
            sfr[ks] = *(const short8*)&Sgt[(wn * 16 + lr) * 288 + ks * 32 + quad * 8];

        if (tid < 256) {
            int s = tid >> 2, f4 = (tid & 3) * 4;
            const float* base = &qkv[(size_t)(c * 64 + s) * 1152 + h * 16];
            float4 qv = *(const float4*)&base[f4];
            float4 kv = *(const float4*)&base[192 + f4];
            sm.c.Qc[s][f4 + 0] = qv.x; sm.c.Qc[s][f4 + 1] = qv.y;
            sm.c.Qc[s][f4 + 2] = qv.z; sm.c.Qc[s][f4 + 3] = qv.w;
            *(ushort4*)&sm.c.Aq[s][f4] = make_ushort4(f2bf(qv.x), f2bf(qv.y), f2bf(qv.z), f2bf(qv.w));
            *(ushort4*)&sm.c.Kb[s][f4] = make_ushort4(f2bf(kv.x), f2bf(kv.y), f2bf(kv.z), f2bf(kv.w));
            *(ushort4*)&sm.c.Aq[s][16 + (tid & 3) * 4] = make_ushort4(0, 0, 0, 0);
            *(ushort4*)&sm.c.Kb[s][16 + (tid & 3) * 4] = make_ushort4(0, 0, 0, 0);
        }
        #pragma unroll
        for (int l = 0; l < 2; ++l) {                    // V -> Vt[d][s]
            int idx = tid + l * 512;
            int ss = idx >> 4, d4 = (idx & 15) * 4;
            float4 vv = *(const float4*)&qkv[(size_t)(c * 64 + ss) * 1152 + 384 + h * 64 + d4];
            sm.c.Vt[d4 + 0][ss] = f2bf(vv.x);
            sm.c.Vt[d4 + 1][ss] = f2bf(vv.y);
            sm.c.Vt[d4 + 2][ss] = f2bf(vv.z);
            sm.c.Vt[d4 + 3][ss] = f2bf(vv.w);
        }
        const float* zg = zb + (h * 16 + c) * 273;
        for (int idx = tid; idx < 288; idx += 512) sm.c.zl[idx] = (idx < 273) ? zg[idx] : 0.f;
        __syncthreads();

        // QK^T: wave tile = rows wm*32 + mi*16, cols wn*16
        f32x4 accS[2] = {{0.f,0.f,0.f,0.f},{0.f,0.f,0.f,0.f}};
        {
            short8 bfr = *(const short8*)&sm.c.Kb[wn * 16 + lr][quad * 8];
            #pragma unroll
            for (int mi = 0; mi < 2; ++mi) {
                short8 af = *(const short8*)&sm.c.Aq[wm * 32 + mi * 16 + lr][quad * 8];
                accS[mi] = __builtin_amdgcn_mfma_f32_16x16x32_bf16(af, bfr, accS[mi], 0, 0, 0);
            }
        }

        // feature map rows + denominator partials: wave handles n in [wave*36, wave*36+36)
        {
            int i = lane;
            float qr[16];
            #pragma unroll
            for (int f = 0; f < 16; ++f) qr[f] = sm.c.Qc[i][f];
            float dp = 0.f;
            int n0 = wave * 36;
            for (int n = n0; n < n0 + 36; ++n) {
                float ph;
                if (n == 0) ph = 1.f;
                else if (n < 17) ph = qr[n - 1] * 0.5f;
                else if (n < 273) { int m = n - 17; ph = qr[m >> 4] * qr[m & 15] * C2; }
                else ph = 0.f;
                sm.c.Pq[i][n] = f2bf(ph);
                dp += ph * sm.c.zl[n];
            }
            sm.c.dpart[wave][i] = dp;
        }

        // causal quadratic scores + per-quarter row sums
        #pragma unroll
        for (int mi = 0; mi < 2; ++mi) {
            float rs[4];
            #pragma unroll
            for (int r = 0; r < 4; ++r) {
                int i = wm * 32 + mi * 16 + quad * 4 + r;
                int j = wn * 16 + lr;
                float u = accS[mi][r];
                float sc = (j <= i) ? (1.f + 0.25f * u + u * u * (1.f / 32.f)) : 0.f;
                rs[r] = sc;
                sm.c.Pq[i][288 + j] = f2bf(sc);
            }
            #pragma unroll
            for (int r = 0; r < 4; ++r) {
                float v = rs[r];
                v += __shfl_xor(v, 1);
                v += __shfl_xor(v, 2);
                v += __shfl_xor(v, 4);
                v += __shfl_xor(v, 8);
                if (lr == 0) sm.c.dpart[8 + wn][wm * 32 + mi * 16 + quad * 4 + r] = v;
            }
        }
        __syncthreads();

        // final GEMM: y_tile = Pq(64x352) @ [S_T | V]^T, wave tile 32x16
        f32x4 acc[2] = {{0.f,0.f,0.f,0.f},{0.f,0.f,0.f,0.f}};
        #pragma unroll
        for (int ks = 0; ks < 11; ++ks) {
            short8 bfr = (ks < 9)
                ? sfr[ks]
                : *(const short8*)&sm.c.Vt[wn * 16 + lr][(ks - 9) * 32 + quad * 8];
            #pragma unroll
            for (int mi = 0; mi < 2; ++mi) {
                short8 af = *(const short8*)&sm.c.Pq[wm * 32 + mi * 16 + lr][ks * 32 + quad * 8];
                acc[mi] = __builtin_amdgcn_mfma_f32_16x16x32_bf16(af, bfr, acc[mi], 0, 0, 0);
            }
        }

        #pragma unroll
        for (int mi = 0; mi < 2; ++mi)
            #pragma unroll
            for (int r = 0; r < 4; ++r) {
                int i = wm * 32 + mi * 16 + quad * 4 + r;
                float den = 1e-12f;
                #pragma unroll
                for (int w = 0; w < 12; ++w) den += sm.c.dpart[w][i];
                float rden = 1.f / den;
                y[(size_t)(c * 64 + i) * 768 + h * 64 + wn * 16 + lr] = acc[mi][r] * rden;
            }
    }
}

extern "C" void kernel_launch(void* const* d_in, const int* in_sizes, int n_in,
                              void* d_out, int out_size, void* d_ws, size_t ws_size,
                              hipStream_t stream) {
    const float* hs = (const float*)d_in[0];
    const float* Wq = (const float*)d_in[1];
    const float* Wk = (const float*)d_in[2];
    const float* Wv = (const float*)d_in[3];
    const float* Wo = (const float*)d_in[4];
    float* out = (float*)d_out;
    float* ws  = (float*)d_ws;

    // Workspace layout (unchanged): St is bf16 S_T[12*16][64][288] inside the old Sb slot.
    float* qkv = ws;                                        // 1024*1152 floats
    float* yb  = ws + 1179648;                              // 1024*768
    unsigned short* St = (unsigned short*)(ws + 1966080);   // 12*16*64*288 ushorts
    float* zb  = ws + 5320704;                              // 12*16*273
    int* bar   = (int*)(ws + 5373184);                      // 2 ints, grid-barrier state

    gemm_qkv_mfma<<<dim3(18, 16), 512, 0, stream>>>(hs, Wq, Wk, Wv, qkv, bar);
    fused_attn  <<<192, 512, 0, stream>>>(qkv, St, zb, yb, bar);
    gemm_wo_mfma<<<dim3(12, 16), 512, 0, stream>>>(yb, Wo, out);
}

// Round 4
// 120.502 us; speedup vs baseline: 1.4408x; 1.4408x over previous
//
#include <hip/hip_runtime.h>

#define C2 0.17677669529663687f  // 1/(4*sqrt(2))

typedef __attribute__((ext_vector_type(8))) short short8;
typedef __attribute__((ext_vector_type(8))) unsigned short ushort8;
typedef __attribute__((ext_vector_type(4))) float f32x4;

// fp32 -> bf16 round-to-nearest-even
__device__ __forceinline__ unsigned short f2bf(float x) {
    union { float f; unsigned u; } v; v.f = x;
    unsigned r = v.u + 0x7fffu + ((v.u >> 16) & 1u);
    return (unsigned short)(r >> 16);
}
__device__ __forceinline__ float bf2f(unsigned short u) {
    union { unsigned u; float f; } v; v.u = ((unsigned)u) << 16;
    return v.f;
}

// ---------------- in-block split-K MFMA GEMM (unchanged, verified) ----------------
__device__ __forceinline__ void gemm_inblk_splitk(
    const float* __restrict__ A, const float* __restrict__ W,
    float* __restrict__ out, int row0, int n0, int outcol0, int ldw, int outld)
{
    __shared__ unsigned short Al[2][2][64][40];   // [group][buf]
    __shared__ unsigned short Bl[2][2][64][40];
    __shared__ float red[64][65];
    const int tid = threadIdx.x;            // 0..511
    const int g = tid >> 8;                 // K-group
    const int t = tid & 255;
    const int lane = t & 63, wave4 = t >> 6;
    const int wm = wave4 & 1, wn = wave4 >> 1;
    const int quad = lane >> 4, lr = lane & 15;
    const int k0base = g * 384;

    f32x4 acc[2][2] = {{{0.f,0.f,0.f,0.f},{0.f,0.f,0.f,0.f}},
                       {{0.f,0.f,0.f,0.f},{0.f,0.f,0.f,0.f}}};

    float4 ra[2], rb[2];
    #pragma unroll
    for (int l = 0; l < 2; ++l) {
        int idx = t + l * 256;
        ra[l] = *(const float4*)&A[(size_t)(row0 + (idx >> 3)) * 768 + k0base + (idx & 7) * 4];
        rb[l] = *(const float4*)&W[(size_t)(k0base + (idx >> 4)) * ldw + n0 + (idx & 15) * 4];
    }
    #pragma unroll
    for (int l = 0; l < 2; ++l) {
        int idx = t + l * 256;
        *(ushort4*)&Al[g][0][idx >> 3][(idx & 7) * 4] =
            make_ushort4(f2bf(ra[l].x), f2bf(ra[l].y), f2bf(ra[l].z), f2bf(ra[l].w));
        int kr = idx >> 4, nq = (idx & 15) * 4;
        int col = (((kr >> 3) ^ ((idx & 15) >> 2)) << 3) | (kr & 7);
        Bl[g][0][nq + 0][col] = f2bf(rb[l].x);
        Bl[g][0][nq + 1][col] = f2bf(rb[l].y);
        Bl[g][0][nq + 2][col] = f2bf(rb[l].z);
        Bl[g][0][nq + 3][col] = f2bf(rb[l].w);
    }
    __syncthreads();

    const int ITER = 12;   // 384 / 32
    #pragma unroll
    for (int i = 0; i < ITER; ++i) {
        const int cur = i & 1, nxt = cur ^ 1;
        float4 na[2], nb[2];
        if (i + 1 < ITER) {
            int kn = k0base + (i + 1) * 32;
            #pragma unroll
            for (int l = 0; l < 2; ++l) {
                int idx = t + l * 256;
                na[l] = *(const float4*)&A[(size_t)(row0 + (idx >> 3)) * 768 + kn + (idx & 7) * 4];
                nb[l] = *(const float4*)&W[(size_t)(kn + (idx >> 4)) * ldw + n0 + (idx & 15) * 4];
            }
        }
        short8 af[2], bfr[2];
        #pragma unroll
        for (int mi = 0; mi < 2; ++mi)
            af[mi] = *(const short8*)&Al[g][cur][wm * 32 + mi * 16 + lr][quad << 3];
        #pragma unroll
        for (int ni = 0; ni < 2; ++ni) {
            int csw = quad ^ ((wn * 2 + ni) & 3);
            bfr[ni] = *(const short8*)&Bl[g][cur][wn * 32 + ni * 16 + lr][csw << 3];
        }
        #pragma unroll
        for (int mi = 0; mi < 2; ++mi)
            #pragma unroll
            for (int ni = 0; ni < 2; ++ni)
                acc[mi][ni] = __builtin_amdgcn_mfma_f32_16x16x32_bf16(af[mi], bfr[ni], acc[mi][ni], 0, 0, 0);
        if (i + 1 < ITER) {
            #pragma unroll
            for (int l = 0; l < 2; ++l) {
                int idx = t + l * 256;
                *(ushort4*)&Al[g][nxt][idx >> 3][(idx & 7) * 4] =
                    make_ushort4(f2bf(na[l].x), f2bf(na[l].y), f2bf(na[l].z), f2bf(na[l].w));
                int kr = idx >> 4, nq = (idx & 15) * 4;
                int col = (((kr >> 3) ^ ((idx & 15) >> 2)) << 3) | (kr & 7);
                Bl[g][nxt][nq + 0][col] = f2bf(nb[l].x);
                Bl[g][nxt][nq + 1][col] = f2bf(nb[l].y);
                Bl[g][nxt][nq + 2][col] = f2bf(nb[l].z);
                Bl[g][nxt][nq + 3][col] = f2bf(nb[l].w);
            }
        }
        __syncthreads();
    }
    if (g == 1) {
        #pragma unroll
        for (int mi = 0; mi < 2; ++mi)
            #pragma unroll
            for (int ni = 0; ni < 2; ++ni)
                #pragma unroll
                for (int r = 0; r < 4; ++r)
                    red[wm * 32 + mi * 16 + quad * 4 + r][wn * 32 + ni * 16 + lr] = acc[mi][ni][r];
    }
    __syncthreads();
    if (g == 0) {
        #pragma unroll
        for (int mi = 0; mi < 2; ++mi)
            #pragma unroll
            for (int ni = 0; ni < 2; ++ni)
                #pragma unroll
                for (int r = 0; r < 4; ++r) {
                    int rr = wm * 32 + mi * 16 + quad * 4 + r;
                    int cc = wn * 32 + ni * 16 + lr;
                    out[(size_t)(row0 + rr) * outld + outcol0 + cc] = acc[mi][ni][r] + red[rr][cc];
                }
    }
}

// qkv: hidden(1024x768) @ [Wq|Wk|Wv] -> qkv(1024x1152). grid (18,16) x 512
__global__ __launch_bounds__(512) void gemm_qkv_mfma(
    const float* __restrict__ H, const float* __restrict__ Wq,
    const float* __restrict__ Wk, const float* __restrict__ Wv,
    float* __restrict__ out)
{
    const int nt = blockIdx.x, mt = blockIdx.y;
    const float* W; int ldw, n0;
    if (nt < 3)      { W = Wq; ldw = 192; n0 = nt * 64; }
    else if (nt < 6) { W = Wk; ldw = 192; n0 = (nt - 3) * 64; }
    else             { W = Wv; ldw = 768; n0 = (nt - 6) * 64; }
    gemm_inblk_splitk(H, W, out, mt * 64, n0, nt * 64, ldw, 1152);
}

// wo: y(1024x768) @ Wo(768x768) -> out(1024x768). grid (12,16) x 512
__global__ __launch_bounds__(512) void gemm_wo_mfma(
    const float* __restrict__ Y, const float* __restrict__ Wo, float* __restrict__ out)
{
    const int nt = blockIdx.x, mt = blockIdx.y;
    gemm_inblk_splitk(Y, Wo, out, mt * 64, nt * 64, nt * 64, 768, 768);
}

// ---------------- per-chunk state via MFMA -> S_T bf16 (512 thr, 8-wave; round-3 verified body) ----
// S_T[h][c][d][n] (ld=288, bf16), pad cols [273,288) zeroed. grid (16,12) x 512. ~60.5 KB LDS.
__global__ __launch_bounds__(512) void chunk_state_k(
    const float* __restrict__ qkv, unsigned short* __restrict__ St, float* __restrict__ zb)
{
    const int c = blockIdx.x, h = blockIdx.y;
    __shared__ float Kc[64][17];
    __shared__ unsigned short Pk[320][72];
    __shared__ unsigned short Vt[80][72];
    const int tid = threadIdx.x;
    const int lane = tid & 63, wave = tid >> 6;       // 8 waves
    const int quad = lane >> 4, lr = lane & 15;

    if (tid < 256) {
        int s = tid >> 2, f4 = (tid & 3) * 4;
        float4 kv = *(const float4*)&qkv[(size_t)(c * 64 + s) * 1152 + 192 + h * 16 + f4];
        Kc[s][f4 + 0] = kv.x; Kc[s][f4 + 1] = kv.y; Kc[s][f4 + 2] = kv.z; Kc[s][f4 + 3] = kv.w;
    }
    #pragma unroll
    for (int l = 0; l < 2; ++l) {
        int idx = tid + l * 512;
        int s = idx >> 4, d4 = (idx & 15) * 4;
        float4 vv = *(const float4*)&qkv[(size_t)(c * 64 + s) * 1152 + 384 + h * 64 + d4];
        Vt[d4 + 0][s] = f2bf(vv.x);
        Vt[d4 + 1][s] = f2bf(vv.y);
        Vt[d4 + 2][s] = f2bf(vv.z);
        Vt[d4 + 3][s] = f2bf(vv.w);
    }
    for (int idx = tid; idx < 16 * 72; idx += 512) {
        int rr = 64 + idx / 72, ss = idx % 72;
        Vt[rr][ss] = (rr == 64 && ss < 64) ? (unsigned short)0x3F80 : (unsigned short)0;
    }
    __syncthreads();
    for (int idx = tid; idx < 2880; idx += 512) {
        int n = idx / 9, s8 = (idx % 9) * 8;
        short8 v8;
        #pragma unroll
        for (int tt = 0; tt < 8; ++tt) {
            int s = s8 + tt;
            float ph = 0.f;
            if (s < 64 && n < 273) {
                if (n == 0) ph = 1.f;
                else if (n < 17) ph = Kc[s][n - 1] * 0.5f;
                else { int m = n - 17; ph = Kc[s][m >> 4] * Kc[s][m & 15] * C2; }
            }
            v8[tt] = (short)f2bf(ph);
        }
        *(short8*)&Pk[n][s8] = v8;
    }
    __syncthreads();

    // 20 feature n-tiles over 8 waves: wave w owns tiles w, w+8, w+16(<20)
    f32x4 acc[5][3];
    #pragma unroll
    for (int mt = 0; mt < 5; ++mt)
        #pragma unroll
        for (int nt = 0; nt < 3; ++nt) acc[mt][nt] = (f32x4){0.f, 0.f, 0.f, 0.f};
    #pragma unroll
    for (int ks = 0; ks < 2; ++ks) {
        short8 af[5], bfr[3];
        #pragma unroll
        for (int mt = 0; mt < 5; ++mt)
            af[mt] = *(const short8*)&Vt[mt * 16 + lr][ks * 32 + quad * 8];
        #pragma unroll
        for (int nt = 0; nt < 3; ++nt)
            if (wave + 8 * nt < 20)
                bfr[nt] = *(const short8*)&Pk[(wave + 8 * nt) * 16 + lr][ks * 32 + quad * 8];
        #pragma unroll
        for (int mt = 0; mt < 5; ++mt)
            #pragma unroll
            for (int nt = 0; nt < 3; ++nt)
                if (wave + 8 * nt < 20)
                    acc[mt][nt] = __builtin_amdgcn_mfma_f32_16x16x32_bf16(af[mt], bfr[nt], acc[mt][nt], 0, 0, 0);
    }
    unsigned short* Sbt = St + (size_t)(h * 16 + c) * 18432;
    float* zp = zb + (h * 16 + c) * 273;
    #pragma unroll
    for (int nt = 0; nt < 3; ++nt) {
        int tile = wave + 8 * nt;
        if (tile < 20) {
            int n = tile * 16 + lr;
            if (n < 288) {
                #pragma unroll
                for (int mt = 0; mt < 4; ++mt)
                    #pragma unroll
                    for (int r = 0; r < 4; ++r)
                        Sbt[(mt * 16 + quad * 4 + r) * 288 + n] =
                            (n < 273) ? f2bf(acc[mt][nt][r]) : (unsigned short)0;
                if (quad == 0 && n < 273) zp[n] = acc[4][nt][0];   // d==64 ones-row -> z
            }
        }
    }
}

// ---------------- exclusive prefix over 16 chunks (batched loads; verified) ----------------
__global__ __launch_bounds__(256) void scan_state_k(unsigned short* __restrict__ St, float* __restrict__ z)
{
    const int NV = 12 * 64 * 36;   // ushort8 chains over all 288 cols (incl. zero pad)
    int gid = blockIdx.x * 256 + threadIdx.x;
    if (gid < NV) {
        int hh = gid / (64 * 36), rem = gid % (64 * 36);
        int d = rem / 36, nb = rem % 36;
        unsigned short* p = St + (size_t)hh * 16 * 18432 + d * 288 + nb * 8;
        ushort8 v[16];
        #pragma unroll
        for (int cc = 0; cc < 16; ++cc) v[cc] = *(const ushort8*)(p + (size_t)cc * 18432);
        float run[8] = {0.f,0.f,0.f,0.f,0.f,0.f,0.f,0.f};
        #pragma unroll
        for (int cc = 0; cc < 16; ++cc) {
            ushort8 w;
            #pragma unroll
            for (int j = 0; j < 8; ++j) {
                w[j] = f2bf(run[j]);
                run[j] += bf2f(v[cc][j]);
            }
            *(ushort8*)(p + (size_t)cc * 18432) = w;
        }
    } else if (gid < NV + 12 * 273) {
        int e2 = gid - NV, hh = e2 / 273, n = e2 % 273;
        float* p = z + hh * 16 * 273 + n;
        float v[16];
        #pragma unroll
        for (int cc = 0; cc < 16; ++cc) v[cc] = p[cc * 273];
        float run = 0.f;
        #pragma unroll
        for (int cc = 0; cc < 16; ++cc) { p[cc * 273] = run; run += v[cc]; }
    }
}

// ---------------- per-chunk output (512 thr, 8-wave 2x4 grid; round-3 verified body) ----------------
// grid (16,12) x 512. ~72.4 KB LDS -> 2 blocks/CU. State B-fragments direct from global.
__global__ __launch_bounds__(512) void chunk_out_k(
    const float* __restrict__ qkv, const unsigned short* __restrict__ St, const float* __restrict__ z,
    float* __restrict__ y)
{
    const int c = blockIdx.x, h = blockIdx.y;
    __shared__ float Qc[64][17];
    __shared__ unsigned short Aq[64][40];
    __shared__ unsigned short Kb[64][40];
    __shared__ unsigned short Pq[64][360];
    __shared__ unsigned short Vt[64][72];
    __shared__ float zl[288];
    __shared__ float dpart[12][64];
    const int tid = threadIdx.x;
    const int lane = tid & 63, wave = tid >> 6;       // 8 waves
    const int quad = lane >> 4, lr = lane & 15;
    const int wm = wave & 1, wn = wave >> 1;          // 2x4 wave grid (32-row x 16-col tiles)

    // state B-fragments from global (post-scan): issue first, consumed in final GEMM only
    const unsigned short* Sgt = St + (size_t)(h * 16 + c) * 18432;
    short8 sfr[9];
    #pragma unroll
    for (int ks = 0; ks < 9; ++ks)
        sfr[ks] = *(const short8*)&Sgt[(wn * 16 + lr) * 288 + ks * 32 + quad * 8];

    if (tid < 256) {
        int s = tid >> 2, f4 = (tid & 3) * 4;
        const float* base = &qkv[(size_t)(c * 64 + s) * 1152 + h * 16];
        float4 qv = *(const float4*)&base[f4];
        float4 kv = *(const float4*)&base[192 + f4];
        Qc[s][f4 + 0] = qv.x; Qc[s][f4 + 1] = qv.y; Qc[s][f4 + 2] = qv.z; Qc[s][f4 + 3] = qv.w;
        *(ushort4*)&Aq[s][f4] = make_ushort4(f2bf(qv.x), f2bf(qv.y), f2bf(qv.z), f2bf(qv.w));
        *(ushort4*)&Kb[s][f4] = make_ushort4(f2bf(kv.x), f2bf(kv.y), f2bf(kv.z), f2bf(kv.w));
        *(ushort4*)&Aq[s][16 + (tid & 3) * 4] = make_ushort4(0, 0, 0, 0);
        *(ushort4*)&Kb[s][16 + (tid & 3) * 4] = make_ushort4(0, 0, 0, 0);
    }
    #pragma unroll
    for (int l = 0; l < 2; ++l) {                    // V -> Vt[d][s]
        int idx = tid + l * 512;
        int ss = idx >> 4, d4 = (idx & 15) * 4;
        float4 vv = *(const float4*)&qkv[(size_t)(c * 64 + ss) * 1152 + 384 + h * 64 + d4];
        Vt[d4 + 0][ss] = f2bf(vv.x);
        Vt[d4 + 1][ss] = f2bf(vv.y);
        Vt[d4 + 2][ss] = f2bf(vv.z);
        Vt[d4 + 3][ss] = f2bf(vv.w);
    }
    const float* zg = z + (h * 16 + c) * 273;
    for (int idx = tid; idx < 288; idx += 512) zl[idx] = (idx < 273) ? zg[idx] : 0.f;
    __syncthreads();

    // QK^T: wave tile = rows wm*32 + mi*16, cols wn*16
    f32x4 accS[2] = {{0.f,0.f,0.f,0.f},{0.f,0.f,0.f,0.f}};
    {
        short8 bfr = *(const short8*)&Kb[wn * 16 + lr][quad * 8];
        #pragma unroll
        for (int mi = 0; mi < 2; ++mi) {
            short8 af = *(const short8*)&Aq[wm * 32 + mi * 16 + lr][quad * 8];
            accS[mi] = __builtin_amdgcn_mfma_f32_16x16x32_bf16(af, bfr, accS[mi], 0, 0, 0);
        }
    }

    // feature map rows + denominator partials: wave handles n in [wave*36, wave*36+36)
    {
        int i = lane;
        float qr[16];
        #pragma unroll
        for (int f = 0; f < 16; ++f) qr[f] = Qc[i][f];
        float dp = 0.f;
        int n0 = wave * 36;
        for (int n = n0; n < n0 + 36; ++n) {
            float ph;
            if (n == 0) ph = 1.f;
            else if (n < 17) ph = qr[n - 1] * 0.5f;
            else if (n < 273) { int m = n - 17; ph = qr[m >> 4] * qr[m & 15] * C2; }
            else ph = 0.f;
            Pq[i][n] = f2bf(ph);
            dp += ph * zl[n];
        }
        dpart[wave][i] = dp;
    }

    // causal quadratic scores + per-quarter row sums
    #pragma unroll
    for (int mi = 0; mi < 2; ++mi) {
        float rs[4];
        #pragma unroll
        for (int r = 0; r < 4; ++r) {
            int i = wm * 32 + mi * 16 + quad * 4 + r;
            int j = wn * 16 + lr;
            float u = accS[mi][r];
            float sc = (j <= i) ? (1.f + 0.25f * u + u * u * (1.f / 32.f)) : 0.f;
            rs[r] = sc;
            Pq[i][288 + j] = f2bf(sc);
        }
        #pragma unroll
        for (int r = 0; r < 4; ++r) {
            float v = rs[r];
            v += __shfl_xor(v, 1);
            v += __shfl_xor(v, 2);
            v += __shfl_xor(v, 4);
            v += __shfl_xor(v, 8);
            if (lr == 0) dpart[8 + wn][wm * 32 + mi * 16 + quad * 4 + r] = v;
        }
    }
    __syncthreads();

    // final GEMM: y_tile = Pq(64x352) @ [S_T | V]^T, wave tile 32x16
    f32x4 acc[2] = {{0.f,0.f,0.f,0.f},{0.f,0.f,0.f,0.f}};
    #pragma unroll
    for (int ks = 0; ks < 11; ++ks) {
        short8 bfr = (ks < 9)
            ? sfr[ks]
            : *(const short8*)&Vt[wn * 16 + lr][(ks - 9) * 32 + quad * 8];
        #pragma unroll
        for (int mi = 0; mi < 2; ++mi) {
            short8 af = *(const short8*)&Pq[wm * 32 + mi * 16 + lr][ks * 32 + quad * 8];
            acc[mi] = __builtin_amdgcn_mfma_f32_16x16x32_bf16(af, bfr, acc[mi], 0, 0, 0);
        }
    }

    #pragma unroll
    for (int mi = 0; mi < 2; ++mi)
        #pragma unroll
        for (int r = 0; r < 4; ++r) {
            int i = wm * 32 + mi * 16 + quad * 4 + r;
            float den = 1e-12f;
            #pragma unroll
            for (int w = 0; w < 12; ++w) den += dpart[w][i];
            float rden = 1.f / den;
            y[(size_t)(c * 64 + i) * 768 + h * 64 + wn * 16 + lr] = acc[mi][r] * rden;
        }
}

extern "C" void kernel_launch(void* const* d_in, const int* in_sizes, int n_in,
                              void* d_out, int out_size, void* d_ws, size_t ws_size,
                              hipStream_t stream) {
    const float* hs = (const float*)d_in[0];
    const float* Wq = (const float*)d_in[1];
    const float* Wk = (const float*)d_in[2];
    const float* Wv = (const float*)d_in[3];
    const float* Wo = (const float*)d_in[4];
    float* out = (float*)d_out;
    float* ws  = (float*)d_ws;

    // Workspace layout (unchanged): St is bf16 S_T[12*16][64][288] inside the old Sb slot.
    float* qkv = ws;                                        // 1024*1152 floats
    float* yb  = ws + 1179648;                              // 1024*768
    unsigned short* St = (unsigned short*)(ws + 1966080);   // 12*16*64*288 ushorts
    float* zb  = ws + 5320704;                              // 12*16*273

    gemm_qkv_mfma<<<dim3(18, 16), 512, 0, stream>>>(hs, Wq, Wk, Wv, qkv);
    chunk_state_k<<<dim3(16, 12), 512, 0, stream>>>(qkv, St, zb);
    scan_state_k <<<121, 256, 0, stream>>>(St, zb);
    chunk_out_k  <<<dim3(16, 12), 512, 0, stream>>>(qkv, St, zb, yb);
    gemm_wo_mfma <<<dim3(12, 16), 512, 0, stream>>>(yb, Wo, out);
}

// Round 5
// 118.963 us; speedup vs baseline: 1.4595x; 1.0129x over previous
//
#include <hip/hip_runtime.h>

#define C2 0.17677669529663687f  // 1/(4*sqrt(2))

typedef __attribute__((ext_vector_type(8))) short short8;
typedef __attribute__((ext_vector_type(8))) unsigned short ushort8;
typedef __attribute__((ext_vector_type(4))) float f32x4;

// fp32 -> bf16 round-to-nearest-even
__device__ __forceinline__ unsigned short f2bf(float x) {
    union { float f; unsigned u; } v; v.f = x;
    unsigned r = v.u + 0x7fffu + ((v.u >> 16) & 1u);
    return (unsigned short)(r >> 16);
}
__device__ __forceinline__ float bf2f(unsigned short u) {
    union { unsigned u; float f; } v; v.u = ((unsigned)u) << 16;
    return v.f;
}

// ---------------- one-shot fp32 -> bf16 conversion of hidden + all weights ----------------
// grid 552 x 512 = 282,624 threads x 8 elems = 2,260,992 elems, exact.
__global__ __launch_bounds__(512) void cvt_prep(
    const float* __restrict__ hs, const float* __restrict__ Wq, const float* __restrict__ Wk,
    const float* __restrict__ Wv, const float* __restrict__ Wo,
    unsigned short* __restrict__ Hh, unsigned short* __restrict__ Wqh,
    unsigned short* __restrict__ Wkh, unsigned short* __restrict__ Wvh,
    unsigned short* __restrict__ Woh)
{
    int e8 = (blockIdx.x * 512 + threadIdx.x) * 8;
    const float* src; unsigned short* dst; int off;
    if      (e8 < 786432)  { src = hs; dst = Hh;  off = e8; }
    else if (e8 < 933888)  { src = Wq; dst = Wqh; off = e8 - 786432; }
    else if (e8 < 1081344) { src = Wk; dst = Wkh; off = e8 - 933888; }
    else if (e8 < 1671168) { src = Wv; dst = Wvh; off = e8 - 1081344; }
    else                   { src = Wo; dst = Woh; off = e8 - 1671168; }
    float4 a = *(const float4*)&src[off];
    float4 b = *(const float4*)&src[off + 4];
    ushort8 o;
    o[0] = f2bf(a.x); o[1] = f2bf(a.y); o[2] = f2bf(a.z); o[3] = f2bf(a.w);
    o[4] = f2bf(b.x); o[5] = f2bf(b.y); o[6] = f2bf(b.z); o[7] = f2bf(b.w);
    *(ushort8*)&dst[off] = o;
}

// ---------------- in-block split-K MFMA GEMM, bf16-staged ----------------
// Same verified structure (2 K-groups x 4 waves, 64x64 tile, BK=32 x 12, register-prefetch
// double-buffered LDS, in-LDS split-K reduce). Staging now loads bf16 ushort8 directly:
// half the global bytes, zero in-loop conversions. LDS layout/swizzle/MFMA loop unchanged.
__device__ __forceinline__ void gemm_inblk_splitk_h(
    const unsigned short* __restrict__ A,   // bf16, ld = 768
    const unsigned short* __restrict__ W,   // bf16, ld = ldw
    float* __restrict__ out, unsigned short* __restrict__ outh,
    int row0, int n0, int outcol0, int ldw, int outld, bool write_f32)
{
    __shared__ __align__(16) unsigned short Al[2][2][64][40];   // [group][buf]
    __shared__ __align__(16) unsigned short Bl[2][2][64][40];
    __shared__ float red[64][65];
    const int tid = threadIdx.x;            // 0..511
    const int g = tid >> 8;                 // K-group
    const int t = tid & 255;
    const int lane = t & 63, wave4 = t >> 6;
    const int wm = wave4 & 1, wn = wave4 >> 1;
    const int quad = lane >> 4, lr = lane & 15;
    const int k0base = g * 384;
    const int ar = t >> 2, ak8 = (t & 3) * 8;      // A: 64 rows x 32 k, 1 ushort8/thread
    const int bkr = t >> 3, bn8 = (t & 7) * 8;     // B: 32 k x 64 n, 1 ushort8/thread

    f32x4 acc[2][2] = {{{0.f,0.f,0.f,0.f},{0.f,0.f,0.f,0.f}},
                       {{0.f,0.f,0.f,0.f},{0.f,0.f,0.f,0.f}}};

    {
        ushort8 ra = *(const ushort8*)&A[(size_t)(row0 + ar) * 768 + k0base + ak8];
        ushort8 rb = *(const ushort8*)&W[(size_t)(k0base + bkr) * ldw + n0 + bn8];
        *(ushort8*)&Al[g][0][ar][ak8] = ra;
        #pragma unroll
        for (int j = 0; j < 8; ++j) {
            int n = bn8 + j;
            int col = (((bkr >> 3) ^ (n >> 4)) << 3) | (bkr & 7);
            Bl[g][0][n][col] = rb[j];
        }
    }
    __syncthreads();

    const int ITER = 12;   // 384 / 32
    #pragma unroll
    for (int i = 0; i < ITER; ++i) {
        const int cur = i & 1, nxt = cur ^ 1;
        ushort8 na, nb;
        if (i + 1 < ITER) {
            int kn = k0base + (i + 1) * 32;
            na = *(const ushort8*)&A[(size_t)(row0 + ar) * 768 + kn + ak8];
            nb = *(const ushort8*)&W[(size_t)(kn + bkr) * ldw + n0 + bn8];
        }
        short8 af[2], bfr[2];
        #pragma unroll
        for (int mi = 0; mi < 2; ++mi)
            af[mi] = *(const short8*)&Al[g][cur][wm * 32 + mi * 16 + lr][quad << 3];
        #pragma unroll
        for (int ni = 0; ni < 2; ++ni) {
            int csw = quad ^ ((wn * 2 + ni) & 3);
            bfr[ni] = *(const short8*)&Bl[g][cur][wn * 32 + ni * 16 + lr][csw << 3];
        }
        #pragma unroll
        for (int mi = 0; mi < 2; ++mi)
            #pragma unroll
            for (int ni = 0; ni < 2; ++ni)
                acc[mi][ni] = __builtin_amdgcn_mfma_f32_16x16x32_bf16(af[mi], bfr[ni], acc[mi][ni], 0, 0, 0);
        if (i + 1 < ITER) {
            *(ushort8*)&Al[g][nxt][ar][ak8] = na;
            #pragma unroll
            for (int j = 0; j < 8; ++j) {
                int n = bn8 + j;
                int col = (((bkr >> 3) ^ (n >> 4)) << 3) | (bkr & 7);
                Bl[g][nxt][n][col] = nb[j];
            }
        }
        __syncthreads();
    }
    if (g == 1) {
        #pragma unroll
        for (int mi = 0; mi < 2; ++mi)
            #pragma unroll
            for (int ni = 0; ni < 2; ++ni)
                #pragma unroll
                for (int r = 0; r < 4; ++r)
                    red[wm * 32 + mi * 16 + quad * 4 + r][wn * 32 + ni * 16 + lr] = acc[mi][ni][r];
    }
    __syncthreads();
    if (g == 0) {
        #pragma unroll
        for (int mi = 0; mi < 2; ++mi)
            #pragma unroll
            for (int ni = 0; ni < 2; ++ni)
                #pragma unroll
                for (int r = 0; r < 4; ++r) {
                    int rr = wm * 32 + mi * 16 + quad * 4 + r;
                    int cc = wn * 32 + ni * 16 + lr;
                    float v = acc[mi][ni][r] + red[rr][cc];
                    if (write_f32) out[(size_t)(row0 + rr) * outld + outcol0 + cc] = v;
                    if (outh) outh[(size_t)(row0 + rr) * outld + outcol0 + cc] = f2bf(v);
                }
    }
}

// qkv: hidden_bf16(1024x768) @ [Wq|Wk|Wv]_bf16 -> qkv fp32 (Q,K cols only) + qkvh bf16 (all).
// grid (18,16) x 512
__global__ __launch_bounds__(512) void gemm_qkv_mfma(
    const unsigned short* __restrict__ Hh, const unsigned short* __restrict__ Wqh,
    const unsigned short* __restrict__ Wkh, const unsigned short* __restrict__ Wvh,
    float* __restrict__ out, unsigned short* __restrict__ outh)
{
    const int nt = blockIdx.x, mt = blockIdx.y;
    const unsigned short* W; int ldw, n0;
    if (nt < 3)      { W = Wqh; ldw = 192; n0 = nt * 64; }
    else if (nt < 6) { W = Wkh; ldw = 192; n0 = (nt - 3) * 64; }
    else             { W = Wvh; ldw = 768; n0 = (nt - 6) * 64; }
    gemm_inblk_splitk_h(Hh, W, out, outh, mt * 64, n0, nt * 64, ldw, 1152, nt < 6);
}

// wo: y_bf16(1024x768) @ Wo_bf16(768x768) -> out fp32. grid (12,16) x 512
__global__ __launch_bounds__(512) void gemm_wo_mfma(
    const unsigned short* __restrict__ Yh, const unsigned short* __restrict__ Woh,
    float* __restrict__ out)
{
    const int nt = blockIdx.x, mt = blockIdx.y;
    gemm_inblk_splitk_h(Yh, Woh, out, (unsigned short*)nullptr,
                        mt * 64, nt * 64, nt * 64, 768, 768, true);
}

// ---------------- per-chunk state via MFMA -> S_T bf16 (512 thr, 8-wave; verified body) ----------
// K fp32 from qkv (feature map); V bf16 from qkvh. grid (16,12) x 512.
__global__ __launch_bounds__(512) void chunk_state_k(
    const float* __restrict__ qkv, const unsigned short* __restrict__ qkvh,
    unsigned short* __restrict__ St, float* __restrict__ zb)
{
    const int c = blockIdx.x, h = blockIdx.y;
    __shared__ float Kc[64][17];
    __shared__ unsigned short Pk[320][72];
    __shared__ unsigned short Vt[80][72];
    const int tid = threadIdx.x;
    const int lane = tid & 63, wave = tid >> 6;       // 8 waves
    const int quad = lane >> 4, lr = lane & 15;

    if (tid < 256) {
        int s = tid >> 2, f4 = (tid & 3) * 4;
        float4 kv = *(const float4*)&qkv[(size_t)(c * 64 + s) * 1152 + 192 + h * 16 + f4];
        Kc[s][f4 + 0] = kv.x; Kc[s][f4 + 1] = kv.y; Kc[s][f4 + 2] = kv.z; Kc[s][f4 + 3] = kv.w;
    }
    {
        int s = tid >> 3, d8 = (tid & 7) * 8;          // V: 64 s x 64 d, bf16 direct
        ushort8 vv = *(const ushort8*)&qkvh[(size_t)(c * 64 + s) * 1152 + 384 + h * 64 + d8];
        #pragma unroll
        for (int j = 0; j < 8; ++j) Vt[d8 + j][s] = vv[j];
    }
    for (int idx = tid; idx < 16 * 72; idx += 512) {
        int rr = 64 + idx / 72, ss = idx % 72;
        Vt[rr][ss] = (rr == 64 && ss < 64) ? (unsigned short)0x3F80 : (unsigned short)0;
    }
    __syncthreads();
    for (int idx = tid; idx < 2880; idx += 512) {
        int n = idx / 9, s8 = (idx % 9) * 8;
        short8 v8;
        #pragma unroll
        for (int tt = 0; tt < 8; ++tt) {
            int s = s8 + tt;
            float ph = 0.f;
            if (s < 64 && n < 273) {
                if (n == 0) ph = 1.f;
                else if (n < 17) ph = Kc[s][n - 1] * 0.5f;
                else { int m = n - 17; ph = Kc[s][m >> 4] * Kc[s][m & 15] * C2; }
            }
            v8[tt] = (short)f2bf(ph);
        }
        *(short8*)&Pk[n][s8] = v8;
    }
    __syncthreads();

    // 20 feature n-tiles over 8 waves: wave w owns tiles w, w+8, w+16(<20)
    f32x4 acc[5][3];
    #pragma unroll
    for (int mt = 0; mt < 5; ++mt)
        #pragma unroll
        for (int nt = 0; nt < 3; ++nt) acc[mt][nt] = (f32x4){0.f, 0.f, 0.f, 0.f};
    #pragma unroll
    for (int ks = 0; ks < 2; ++ks) {
        short8 af[5], bfr[3];
        #pragma unroll
        for (int mt = 0; mt < 5; ++mt)
            af[mt] = *(const short8*)&Vt[mt * 16 + lr][ks * 32 + quad * 8];
        #pragma unroll
        for (int nt = 0; nt < 3; ++nt)
            if (wave + 8 * nt < 20)
                bfr[nt] = *(const short8*)&Pk[(wave + 8 * nt) * 16 + lr][ks * 32 + quad * 8];
        #pragma unroll
        for (int mt = 0; mt < 5; ++mt)
            #pragma unroll
            for (int nt = 0; nt < 3; ++nt)
                if (wave + 8 * nt < 20)
                    acc[mt][nt] = __builtin_amdgcn_mfma_f32_16x16x32_bf16(af[mt], bfr[nt], acc[mt][nt], 0, 0, 0);
    }
    unsigned short* Sbt = St + (size_t)(h * 16 + c) * 18432;
    float* zp = zb + (h * 16 + c) * 273;
    #pragma unroll
    for (int nt = 0; nt < 3; ++nt) {
        int tile = wave + 8 * nt;
        if (tile < 20) {
            int n = tile * 16 + lr;
            if (n < 288) {
                #pragma unroll
                for (int mt = 0; mt < 4; ++mt)
                    #pragma unroll
                    for (int r = 0; r < 4; ++r)
                        Sbt[(mt * 16 + quad * 4 + r) * 288 + n] =
                            (n < 273) ? f2bf(acc[mt][nt][r]) : (unsigned short)0;
                if (quad == 0 && n < 273) zp[n] = acc[4][nt][0];   // d==64 ones-row -> z
            }
        }
    }
}

// ---------------- exclusive prefix over 16 chunks (batched loads; verified) ----------------
__global__ __launch_bounds__(256) void scan_state_k(unsigned short* __restrict__ St, float* __restrict__ z)
{
    const int NV = 12 * 64 * 36;   // ushort8 chains over all 288 cols (incl. zero pad)
    int gid = blockIdx.x * 256 + threadIdx.x;
    if (gid < NV) {
        int hh = gid / (64 * 36), rem = gid % (64 * 36);
        int d = rem / 36, nb = rem % 36;
        unsigned short* p = St + (size_t)hh * 16 * 18432 + d * 288 + nb * 8;
        ushort8 v[16];
        #pragma unroll
        for (int cc = 0; cc < 16; ++cc) v[cc] = *(const ushort8*)(p + (size_t)cc * 18432);
        float run[8] = {0.f,0.f,0.f,0.f,0.f,0.f,0.f,0.f};
        #pragma unroll
        for (int cc = 0; cc < 16; ++cc) {
            ushort8 w;
            #pragma unroll
            for (int j = 0; j < 8; ++j) {
                w[j] = f2bf(run[j]);
                run[j] += bf2f(v[cc][j]);
            }
            *(ushort8*)(p + (size_t)cc * 18432) = w;
        }
    } else if (gid < NV + 12 * 273) {
        int e2 = gid - NV, hh = e2 / 273, n = e2 % 273;
        float* p = z + hh * 16 * 273 + n;
        float v[16];
        #pragma unroll
        for (int cc = 0; cc < 16; ++cc) v[cc] = p[cc * 273];
        float run = 0.f;
        #pragma unroll
        for (int cc = 0; cc < 16; ++cc) { p[cc * 273] = run; run += v[cc]; }
    }
}

// ---------------- per-chunk output (512 thr, 8-wave 2x4 grid; verified body) ----------------
// Q fp32 from qkv (feature map); Q/K/V MFMA operands bf16 from qkvh; y written bf16.
__global__ __launch_bounds__(512) void chunk_out_k(
    const float* __restrict__ qkv, const unsigned short* __restrict__ qkvh,
    const unsigned short* __restrict__ St, const float* __restrict__ z,
    unsigned short* __restrict__ y)
{
    const int c = blockIdx.x, h = blockIdx.y;
    __shared__ float Qc[64][17];
    __shared__ unsigned short Aq[64][40];
    __shared__ unsigned short Kb[64][40];
    __shared__ unsigned short Pq[64][360];
    __shared__ unsigned short Vt[64][72];
    __shared__ float zl[288];
    __shared__ float dpart[12][64];
    const int tid = threadIdx.x;
    const int lane = tid & 63, wave = tid >> 6;       // 8 waves
    const int quad = lane >> 4, lr = lane & 15;
    const int wm = wave & 1, wn = wave >> 1;          // 2x4 wave grid (32-row x 16-col tiles)

    // state B-fragments from global (post-scan): issue first, consumed in final GEMM only
    const unsigned short* Sgt = St + (size_t)(h * 16 + c) * 18432;
    short8 sfr[9];
    #pragma unroll
    for (int ks = 0; ks < 9; ++ks)
        sfr[ks] = *(const short8*)&Sgt[(wn * 16 + lr) * 288 + ks * 32 + quad * 8];

    if (tid < 256) {
        int s = tid >> 2, f4 = (tid & 3) * 4;
        float4 qv = *(const float4*)&qkv[(size_t)(c * 64 + s) * 1152 + h * 16 + f4];
        Qc[s][f4 + 0] = qv.x; Qc[s][f4 + 1] = qv.y; Qc[s][f4 + 2] = qv.z; Qc[s][f4 + 3] = qv.w;
        *(ushort4*)&Aq[s][f4] =
            *(const ushort4*)&qkvh[(size_t)(c * 64 + s) * 1152 + h * 16 + f4];
        *(ushort4*)&Kb[s][f4] =
            *(const ushort4*)&qkvh[(size_t)(c * 64 + s) * 1152 + 192 + h * 16 + f4];
        *(ushort4*)&Aq[s][16 + (tid & 3) * 4] = make_ushort4(0, 0, 0, 0);
        *(ushort4*)&Kb[s][16 + (tid & 3) * 4] = make_ushort4(0, 0, 0, 0);
    }
    {
        int ss = tid >> 3, d8 = (tid & 7) * 8;         // V bf16 direct
        ushort8 vv = *(const ushort8*)&qkvh[(size_t)(c * 64 + ss) * 1152 + 384 + h * 64 + d8];
        #pragma unroll
        for (int j = 0; j < 8; ++j) Vt[d8 + j][ss] = vv[j];
    }
    const float* zg = z + (h * 16 + c) * 273;
    for (int idx = tid; idx < 288; idx += 512) zl[idx] = (idx < 273) ? zg[idx] : 0.f;
    __syncthreads();

    // QK^T: wave tile = rows wm*32 + mi*16, cols wn*16
    f32x4 accS[2] = {{0.f,0.f,0.f,0.f},{0.f,0.f,0.f,0.f}};
    {
        short8 bfr = *(const short8*)&Kb[wn * 16 + lr][quad * 8];
        #pragma unroll
        for (int mi = 0; mi < 2; ++mi) {
            short8 af = *(const short8*)&Aq[wm * 32 + mi * 16 + lr][quad * 8];
            accS[mi] = __builtin_amdgcn_mfma_f32_16x16x32_bf16(af, bfr, accS[mi], 0, 0, 0);
        }
    }

    // feature map rows + denominator partials: wave handles n in [wave*36, wave*36+36)
    {
        int i = lane;
        float qr[16];
        #pragma unroll
        for (int f = 0; f < 16; ++f) qr[f] = Qc[i][f];
        float dp = 0.f;
        int n0 = wave * 36;
        for (int n = n0; n < n0 + 36; ++n) {
            float ph;
            if (n == 0) ph = 1.f;
            else if (n < 17) ph = qr[n - 1] * 0.5f;
            else if (n < 273) { int m = n - 17; ph = qr[m >> 4] * qr[m & 15] * C2; }
            else ph = 0.f;
            Pq[i][n] = f2bf(ph);
            dp += ph * zl[n];
        }
        dpart[wave][i] = dp;
    }

    // causal quadratic scores + per-quarter row sums
    #pragma unroll
    for (int mi = 0; mi < 2; ++mi) {
        float rs[4];
        #pragma unroll
        for (int r = 0; r < 4; ++r) {
            int i = wm * 32 + mi * 16 + quad * 4 + r;
            int j = wn * 16 + lr;
            float u = accS[mi][r];
            float sc = (j <= i) ? (1.f + 0.25f * u + u * u * (1.f / 32.f)) : 0.f;
            rs[r] = sc;
            Pq[i][288 + j] = f2bf(sc);
        }
        #pragma unroll
        for (int r = 0; r < 4; ++r) {
            float v = rs[r];
            v += __shfl_xor(v, 1);
            v += __shfl_xor(v, 2);
            v += __shfl_xor(v, 4);
            v += __shfl_xor(v, 8);
            if (lr == 0) dpart[8 + wn][wm * 32 + mi * 16 + quad * 4 + r] = v;
        }
    }
    __syncthreads();

    // final GEMM: y_tile = Pq(64x352) @ [S_T | V]^T, wave tile 32x16
    f32x4 acc[2] = {{0.f,0.f,0.f,0.f},{0.f,0.f,0.f,0.f}};
    #pragma unroll
    for (int ks = 0; ks < 11; ++ks) {
        short8 bfr = (ks < 9)
            ? sfr[ks]
            : *(const short8*)&Vt[wn * 16 + lr][(ks - 9) * 32 + quad * 8];
        #pragma unroll
        for (int mi = 0; mi < 2; ++mi) {
            short8 af = *(const short8*)&Pq[wm * 32 + mi * 16 + lr][ks * 32 + quad * 8];
            acc[mi] = __builtin_amdgcn_mfma_f32_16x16x32_bf16(af, bfr, acc[mi], 0, 0, 0);
        }
    }

    #pragma unroll
    for (int mi = 0; mi < 2; ++mi)
        #pragma unroll
        for (int r = 0; r < 4; ++r) {
            int i = wm * 32 + mi * 16 + quad * 4 + r;
            float den = 1e-12f;
            #pragma unroll
            for (int w = 0; w < 12; ++w) den += dpart[w][i];
            float rden = 1.f / den;
            y[(size_t)(c * 64 + i) * 768 + h * 64 + wn * 16 + lr] = f2bf(acc[mi][r] * rden);
        }
}

extern "C" void kernel_launch(void* const* d_in, const int* in_sizes, int n_in,
                              void* d_out, int out_size, void* d_ws, size_t ws_size,
                              hipStream_t stream) {
    const float* hs = (const float*)d_in[0];
    const float* Wq = (const float*)d_in[1];
    const float* Wk = (const float*)d_in[2];
    const float* Wv = (const float*)d_in[3];
    const float* Wo = (const float*)d_in[4];
    float* out = (float*)d_out;
    float* ws  = (float*)d_ws;

    // Workspace layout (float offsets; all 16B-aligned):
    float*          qkv  = ws;                                   // 1024x1152 fp32 (Q,K cols only)
    unsigned short* qkvh = (unsigned short*)(ws + 1179648);      // 1024x1152 bf16
    unsigned short* yb   = (unsigned short*)(ws + 1769472);      // 1024x768  bf16
    unsigned short* St   = (unsigned short*)(ws + 2162688);      // 12*16*64*288 bf16
    float*          zb   = ws + 3932160;                         // 12*16*273 fp32
    unsigned short* Hh   = (unsigned short*)(ws + 3984576);      // 1024x768 bf16
    unsigned short* Wqh  = (unsigned short*)(ws + 4377792);      // 768x192 bf16
    unsigned short* Wkh  = (unsigned short*)(ws + 4451520);      // 768x192 bf16
    unsigned short* Wvh  = (unsigned short*)(ws + 4525248);      // 768x768 bf16
    unsigned short* Woh  = (unsigned short*)(ws + 4820160);      // 768x768 bf16

    cvt_prep     <<<552, 512, 0, stream>>>(hs, Wq, Wk, Wv, Wo, Hh, Wqh, Wkh, Wvh, Woh);
    gemm_qkv_mfma<<<dim3(18, 16), 512, 0, stream>>>(Hh, Wqh, Wkh, Wvh, qkv, qkvh);
    chunk_state_k<<<dim3(16, 12), 512, 0, stream>>>(qkv, qkvh, St, zb);
    scan_state_k <<<121, 256, 0, stream>>>(St, zb);
    chunk_out_k  <<<dim3(16, 12), 512, 0, stream>>>(qkv, qkvh, St, zb, yb);
    gemm_wo_mfma <<<dim3(12, 16), 512, 0, stream>>>(yb, Woh, out);
}

// Round 6
// 118.739 us; speedup vs baseline: 1.4622x; 1.0019x over previous
//
#include <hip/hip_runtime.h>

#define C2 0.17677669529663687f  // 1/(4*sqrt(2))

typedef __attribute__((ext_vector_type(8))) short short8;
typedef __attribute__((ext_vector_type(8))) unsigned short ushort8;
typedef __attribute__((ext_vector_type(4))) float f32x4;

// fp32 -> bf16 round-to-nearest-even
__device__ __forceinline__ unsigned short f2bf(float x) {
    union { float f; unsigned u; } v; v.f = x;
    unsigned r = v.u + 0x7fffu + ((v.u >> 16) & 1u);
    return (unsigned short)(r >> 16);
}
__device__ __forceinline__ float bf2f(unsigned short u) {
    union { unsigned u; float f; } v; v.u = ((unsigned)u) << 16;
    return v.f;
}

// ---------------- one-shot fp32 -> bf16 conversion of hidden + all weights ----------------
// grid 552 x 512 = 282,624 threads x 8 elems = 2,260,992 elems, exact.
__global__ __launch_bounds__(512) void cvt_prep(
    const float* __restrict__ hs, const float* __restrict__ Wq, const float* __restrict__ Wk,
    const float* __restrict__ Wv, const float* __restrict__ Wo,
    unsigned short* __restrict__ Hh, unsigned short* __restrict__ Wqh,
    unsigned short* __restrict__ Wkh, unsigned short* __restrict__ Wvh,
    unsigned short* __restrict__ Woh)
{
    int e8 = (blockIdx.x * 512 + threadIdx.x) * 8;
    const float* src; unsigned short* dst; int off;
    if      (e8 < 786432)  { src = hs; dst = Hh;  off = e8; }
    else if (e8 < 933888)  { src = Wq; dst = Wqh; off = e8 - 786432; }
    else if (e8 < 1081344) { src = Wk; dst = Wkh; off = e8 - 933888; }
    else if (e8 < 1671168) { src = Wv; dst = Wvh; off = e8 - 1081344; }
    else                   { src = Wo; dst = Woh; off = e8 - 1671168; }
    float4 a = *(const float4*)&src[off];
    float4 b = *(const float4*)&src[off + 4];
    ushort8 o;
    o[0] = f2bf(a.x); o[1] = f2bf(a.y); o[2] = f2bf(a.z); o[3] = f2bf(a.w);
    o[4] = f2bf(b.x); o[5] = f2bf(b.y); o[6] = f2bf(b.z); o[7] = f2bf(b.w);
    *(ushort8*)&dst[off] = o;
}

// ---------------- in-block split-K MFMA GEMM, bf16-staged, BK=96 x 4 iters ----------------
// Same verified tile/fragment structure (2 K-groups x 4 waves, 64x64 tile, split-K reduce),
// but 4 barriers instead of 12: each K-step covers 96 k as 3 sub-tiles whose LDS layout and
// index formulas are byte-identical to the old BK=32 code. k-ascending MFMA order preserved
// -> bit-identical numerics. Split-K reduce buffer aliases Bl (dead by then; last read and
// the red-write are separated by the loop's final barrier). LDS = 122,880 B -> 1 block/CU
// (grid never gave 2 resident blocks anyway).
__device__ __forceinline__ void gemm_inblk_splitk_h(
    const unsigned short* __restrict__ A,   // bf16, ld = 768
    const unsigned short* __restrict__ W,   // bf16, ld = ldw
    float* __restrict__ out, unsigned short* __restrict__ outh,
    int row0, int n0, int outcol0, int ldw, int outld, bool write_f32)
{
    __shared__ __align__(16) unsigned short Al[2][2][3][64][40];   // [group][buf][subtile]
    __shared__ __align__(16) unsigned short Bl[2][2][3][64][40];
    float (*red)[65] = (float (*)[65])&Bl[0][0][0][0][0];          // 16,640 B alias, safe post-loop
    const int tid = threadIdx.x;            // 0..511
    const int g = tid >> 8;                 // K-group
    const int t = tid & 255;
    const int lane = t & 63, wave4 = t >> 6;
    const int wm = wave4 & 1, wn = wave4 >> 1;
    const int quad = lane >> 4, lr = lane & 15;
    const int k0base = g * 384;
    const int ar = t >> 2, ak8 = (t & 3) * 8;      // A: 64 rows x 32 k per subtile
    const int bkr = t >> 3, bn8 = (t & 7) * 8;     // B: 32 k x 64 n per subtile

    f32x4 acc[2][2] = {{{0.f,0.f,0.f,0.f},{0.f,0.f,0.f,0.f}},
                       {{0.f,0.f,0.f,0.f},{0.f,0.f,0.f,0.f}}};

    // stage iter 0 (3 subtiles)
    #pragma unroll
    for (int sk = 0; sk < 3; ++sk) {
        ushort8 ra = *(const ushort8*)&A[(size_t)(row0 + ar) * 768 + k0base + sk * 32 + ak8];
        ushort8 rb = *(const ushort8*)&W[(size_t)(k0base + sk * 32 + bkr) * ldw + n0 + bn8];
        *(ushort8*)&Al[g][0][sk][ar][ak8] = ra;
        #pragma unroll
        for (int j = 0; j < 8; ++j) {
            int n = bn8 + j;
            int col = (((bkr >> 3) ^ (n >> 4)) << 3) | (bkr & 7);
            Bl[g][0][sk][n][col] = rb[j];
        }
    }
    __syncthreads();

    const int ITER = 4;   // 384 / 96
    #pragma unroll
    for (int i = 0; i < ITER; ++i) {
        const int cur = i & 1, nxt = cur ^ 1;
        ushort8 na[3], nb[3];
        if (i + 1 < ITER) {
            int kn = k0base + (i + 1) * 96;
            #pragma unroll
            for (int sk = 0; sk < 3; ++sk) {
                na[sk] = *(const ushort8*)&A[(size_t)(row0 + ar) * 768 + kn + sk * 32 + ak8];
                nb[sk] = *(const ushort8*)&W[(size_t)(kn + sk * 32 + bkr) * ldw + n0 + bn8];
            }
        }
        #pragma unroll
        for (int sk = 0; sk < 3; ++sk) {
            short8 af[2], bfr[2];
            #pragma unroll
            for (int mi = 0; mi < 2; ++mi)
                af[mi] = *(const short8*)&Al[g][cur][sk][wm * 32 + mi * 16 + lr][quad << 3];
            #pragma unroll
            for (int ni = 0; ni < 2; ++ni) {
                int csw = quad ^ ((wn * 2 + ni) & 3);
                bfr[ni] = *(const short8*)&Bl[g][cur][sk][wn * 32 + ni * 16 + lr][csw << 3];
            }
            #pragma unroll
            for (int mi = 0; mi < 2; ++mi)
                #pragma unroll
                for (int ni = 0; ni < 2; ++ni)
                    acc[mi][ni] = __builtin_amdgcn_mfma_f32_16x16x32_bf16(af[mi], bfr[ni], acc[mi][ni], 0, 0, 0);
        }
        if (i + 1 < ITER) {
            #pragma unroll
            for (int sk = 0; sk < 3; ++sk) {
                *(ushort8*)&Al[g][nxt][sk][ar][ak8] = na[sk];
                #pragma unroll
                for (int j = 0; j < 8; ++j) {
                    int n = bn8 + j;
                    int col = (((bkr >> 3) ^ (n >> 4)) << 3) | (bkr & 7);
                    Bl[g][nxt][sk][n][col] = nb[sk][j];
                }
            }
        }
        __syncthreads();
    }
    if (g == 1) {
        #pragma unroll
        for (int mi = 0; mi < 2; ++mi)
            #pragma unroll
            for (int ni = 0; ni < 2; ++ni)
                #pragma unroll
                for (int r = 0; r < 4; ++r)
                    red[wm * 32 + mi * 16 + quad * 4 + r][wn * 32 + ni * 16 + lr] = acc[mi][ni][r];
    }
    __syncthreads();
    if (g == 0) {
        #pragma unroll
        for (int mi = 0; mi < 2; ++mi)
            #pragma unroll
            for (int ni = 0; ni < 2; ++ni)
                #pragma unroll
                for (int r = 0; r < 4; ++r) {
                    int rr = wm * 32 + mi * 16 + quad * 4 + r;
                    int cc = wn * 32 + ni * 16 + lr;
                    float v = acc[mi][ni][r] + red[rr][cc];
                    if (write_f32) out[(size_t)(row0 + rr) * outld + outcol0 + cc] = v;
                    if (outh) outh[(size_t)(row0 + rr) * outld + outcol0 + cc] = f2bf(v);
                }
    }
}

// qkv: hidden_bf16(1024x768) @ [Wq|Wk|Wv]_bf16 -> qkv fp32 (Q,K cols only) + qkvh bf16 (all).
// grid (18,16) x 512
__global__ __launch_bounds__(512) void gemm_qkv_mfma(
    const unsigned short* __restrict__ Hh, const unsigned short* __restrict__ Wqh,
    const unsigned short* __restrict__ Wkh, const unsigned short* __restrict__ Wvh,
    float* __restrict__ out, unsigned short* __restrict__ outh)
{
    const int nt = blockIdx.x, mt = blockIdx.y;
    const unsigned short* W; int ldw, n0;
    if (nt < 3)      { W = Wqh; ldw = 192; n0 = nt * 64; }
    else if (nt < 6) { W = Wkh; ldw = 192; n0 = (nt - 3) * 64; }
    else             { W = Wvh; ldw = 768; n0 = (nt - 6) * 64; }
    gemm_inblk_splitk_h(Hh, W, out, outh, mt * 64, n0, nt * 64, ldw, 1152, nt < 6);
}

// wo: y_bf16(1024x768) @ Wo_bf16(768x768) -> out fp32. grid (12,16) x 512
__global__ __launch_bounds__(512) void gemm_wo_mfma(
    const unsigned short* __restrict__ Yh, const unsigned short* __restrict__ Woh,
    float* __restrict__ out)
{
    const int nt = blockIdx.x, mt = blockIdx.y;
    gemm_inblk_splitk_h(Yh, Woh, out, (unsigned short*)nullptr,
                        mt * 64, nt * 64, nt * 64, 768, 768, true);
}

// ---------------- per-chunk state via MFMA -> S_T bf16 (512 thr, 8-wave; verified body) ----------
// K fp32 from qkv (feature map); V bf16 from qkvh. grid (16,12) x 512.
__global__ __launch_bounds__(512) void chunk_state_k(
    const float* __restrict__ qkv, const unsigned short* __restrict__ qkvh,
    unsigned short* __restrict__ St, float* __restrict__ zb)
{
    const int c = blockIdx.x, h = blockIdx.y;
    __shared__ float Kc[64][17];
    __shared__ unsigned short Pk[320][72];
    __shared__ unsigned short Vt[80][72];
    const int tid = threadIdx.x;
    const int lane = tid & 63, wave = tid >> 6;       // 8 waves
    const int quad = lane >> 4, lr = lane & 15;

    if (tid < 256) {
        int s = tid >> 2, f4 = (tid & 3) * 4;
        float4 kv = *(const float4*)&qkv[(size_t)(c * 64 + s) * 1152 + 192 + h * 16 + f4];
        Kc[s][f4 + 0] = kv.x; Kc[s][f4 + 1] = kv.y; Kc[s][f4 + 2] = kv.z; Kc[s][f4 + 3] = kv.w;
    }
    {
        int s = tid >> 3, d8 = (tid & 7) * 8;          // V: 64 s x 64 d, bf16 direct
        ushort8 vv = *(const ushort8*)&qkvh[(size_t)(c * 64 + s) * 1152 + 384 + h * 64 + d8];
        #pragma unroll
        for (int j = 0; j < 8; ++j) Vt[d8 + j][s] = vv[j];
    }
    for (int idx = tid; idx < 16 * 72; idx += 512) {
        int rr = 64 + idx / 72, ss = idx % 72;
        Vt[rr][ss] = (rr == 64 && ss < 64) ? (unsigned short)0x3F80 : (unsigned short)0;
    }
    __syncthreads();
    for (int idx = tid; idx < 2880; idx += 512) {
        int n = idx / 9, s8 = (idx % 9) * 8;
        short8 v8;
        #pragma unroll
        for (int tt = 0; tt < 8; ++tt) {
            int s = s8 + tt;
            float ph = 0.f;
            if (s < 64 && n < 273) {
                if (n == 0) ph = 1.f;
                else if (n < 17) ph = Kc[s][n - 1] * 0.5f;
                else { int m = n - 17; ph = Kc[s][m >> 4] * Kc[s][m & 15] * C2; }
            }
            v8[tt] = (short)f2bf(ph);
        }
        *(short8*)&Pk[n][s8] = v8;
    }
    __syncthreads();

    // 20 feature n-tiles over 8 waves: wave w owns tiles w, w+8, w+16(<20)
    f32x4 acc[5][3];
    #pragma unroll
    for (int mt = 0; mt < 5; ++mt)
        #pragma unroll
        for (int nt = 0; nt < 3; ++nt) acc[mt][nt] = (f32x4){0.f, 0.f, 0.f, 0.f};
    #pragma unroll
    for (int ks = 0; ks < 2; ++ks) {
        short8 af[5], bfr[3];
        #pragma unroll
        for (int mt = 0; mt < 5; ++mt)
            af[mt] = *(const short8*)&Vt[mt * 16 + lr][ks * 32 + quad * 8];
        #pragma unroll
        for (int nt = 0; nt < 3; ++nt)
            if (wave + 8 * nt < 20)
                bfr[nt] = *(const short8*)&Pk[(wave + 8 * nt) * 16 + lr][ks * 32 + quad * 8];
        #pragma unroll
        for (int mt = 0; mt < 5; ++mt)
            #pragma unroll
            for (int nt = 0; nt < 3; ++nt)
                if (wave + 8 * nt < 20)
                    acc[mt][nt] = __builtin_amdgcn_mfma_f32_16x16x32_bf16(af[mt], bfr[nt], acc[mt][nt], 0, 0, 0);
    }
    unsigned short* Sbt = St + (size_t)(h * 16 + c) * 18432;
    float* zp = zb + (h * 16 + c) * 273;
    #pragma unroll
    for (int nt = 0; nt < 3; ++nt) {
        int tile = wave + 8 * nt;
        if (tile < 20) {
            int n = tile * 16 + lr;
            if (n < 288) {
                #pragma unroll
                for (int mt = 0; mt < 4; ++mt)
                    #pragma unroll
                    for (int r = 0; r < 4; ++r)
                        Sbt[(mt * 16 + quad * 4 + r) * 288 + n] =
                            (n < 273) ? f2bf(acc[mt][nt][r]) : (unsigned short)0;
                if (quad == 0 && n < 273) zp[n] = acc[4][nt][0];   // d==64 ones-row -> z
            }
        }
    }
}

// ---------------- exclusive prefix over 16 chunks (batched loads; verified) ----------------
__global__ __launch_bounds__(256) void scan_state_k(unsigned short* __restrict__ St, float* __restrict__ z)
{
    const int NV = 12 * 64 * 36;   // ushort8 chains over all 288 cols (incl. zero pad)
    int gid = blockIdx.x * 256 + threadIdx.x;
    if (gid < NV) {
        int hh = gid / (64 * 36), rem = gid % (64 * 36);
        int d = rem / 36, nb = rem % 36;
        unsigned short* p = St + (size_t)hh * 16 * 18432 + d * 288 + nb * 8;
        ushort8 v[16];
        #pragma unroll
        for (int cc = 0; cc < 16; ++cc) v[cc] = *(const ushort8*)(p + (size_t)cc * 18432);
        float run[8] = {0.f,0.f,0.f,0.f,0.f,0.f,0.f,0.f};
        #pragma unroll
        for (int cc = 0; cc < 16; ++cc) {
            ushort8 w;
            #pragma unroll
            for (int j = 0; j < 8; ++j) {
                w[j] = f2bf(run[j]);
                run[j] += bf2f(v[cc][j]);
            }
            *(ushort8*)(p + (size_t)cc * 18432) = w;
        }
    } else if (gid < NV + 12 * 273) {
        int e2 = gid - NV, hh = e2 / 273, n = e2 % 273;
        float* p = z + hh * 16 * 273 + n;
        float v[16];
        #pragma unroll
        for (int cc = 0; cc < 16; ++cc) v[cc] = p[cc * 273];
        float run = 0.f;
        #pragma unroll
        for (int cc = 0; cc < 16; ++cc) { p[cc * 273] = run; run += v[cc]; }
    }
}

// ---------------- per-chunk output (512 thr, 8-wave 2x4 grid; verified body) ----------------
// Q fp32 from qkv (feature map); Q/K/V MFMA operands bf16 from qkvh; y written bf16.
// s_setprio(1) around the final MFMA cluster (T5: 2 blocks/CU -> genuine wave-role diversity).
__global__ __launch_bounds__(512) void chunk_out_k(
    const float* __restrict__ qkv, const unsigned short* __restrict__ qkvh,
    const unsigned short* __restrict__ St, const float* __restrict__ z,
    unsigned short* __restrict__ y)
{
    const int c = blockIdx.x, h = blockIdx.y;
    __shared__ float Qc[64][17];
    __shared__ unsigned short Aq[64][40];
    __shared__ unsigned short Kb[64][40];
    __shared__ unsigned short Pq[64][360];
    __shared__ unsigned short Vt[64][72];
    __shared__ float zl[288];
    __shared__ float dpart[12][64];
    const int tid = threadIdx.x;
    const int lane = tid & 63, wave = tid >> 6;       // 8 waves
    const int quad = lane >> 4, lr = lane & 15;
    const int wm = wave & 1, wn = wave >> 1;          // 2x4 wave grid (32-row x 16-col tiles)

    // state B-fragments from global (post-scan): issue first, consumed in final GEMM only
    const unsigned short* Sgt = St + (size_t)(h * 16 + c) * 18432;
    short8 sfr[9];
    #pragma unroll
    for (int ks = 0; ks < 9; ++ks)
        sfr[ks] = *(const short8*)&Sgt[(wn * 16 + lr) * 288 + ks * 32 + quad * 8];

    if (tid < 256) {
        int s = tid >> 2, f4 = (tid & 3) * 4;
        float4 qv = *(const float4*)&qkv[(size_t)(c * 64 + s) * 1152 + h * 16 + f4];
        Qc[s][f4 + 0] = qv.x; Qc[s][f4 + 1] = qv.y; Qc[s][f4 + 2] = qv.z; Qc[s][f4 + 3] = qv.w;
        *(ushort4*)&Aq[s][f4] =
            *(const ushort4*)&qkvh[(size_t)(c * 64 + s) * 1152 + h * 16 + f4];
        *(ushort4*)&Kb[s][f4] =
            *(const ushort4*)&qkvh[(size_t)(c * 64 + s) * 1152 + 192 + h * 16 + f4];
        *(ushort4*)&Aq[s][16 + (tid & 3) * 4] = make_ushort4(0, 0, 0, 0);
        *(ushort4*)&Kb[s][16 + (tid & 3) * 4] = make_ushort4(0, 0, 0, 0);
    }
    {
        int ss = tid >> 3, d8 = (tid & 7) * 8;         // V bf16 direct
        ushort8 vv = *(const ushort8*)&qkvh[(size_t)(c * 64 + ss) * 1152 + 384 + h * 64 + d8];
        #pragma unroll
        for (int j = 0; j < 8; ++j) Vt[d8 + j][ss] = vv[j];
    }
    const float* zg = z + (h * 16 + c) * 273;
    for (int idx = tid; idx < 288; idx += 512) zl[idx] = (idx < 273) ? zg[idx] : 0.f;
    __syncthreads();

    // QK^T: wave tile = rows wm*32 + mi*16, cols wn*16
    f32x4 accS[2] = {{0.f,0.f,0.f,0.f},{0.f,0.f,0.f,0.f}};
    {
        short8 bfr = *(const short8*)&Kb[wn * 16 + lr][quad * 8];
        #pragma unroll
        for (int mi = 0; mi < 2; ++mi) {
            short8 af = *(const short8*)&Aq[wm * 32 + mi * 16 + lr][quad * 8];
            accS[mi] = __builtin_amdgcn_mfma_f32_16x16x32_bf16(af, bfr, accS[mi], 0, 0, 0);
        }
    }

    // feature map rows + denominator partials: wave handles n in [wave*36, wave*36+36)
    {
        int i = lane;
        float qr[16];
        #pragma unroll
        for (int f = 0; f < 16; ++f) qr[f] = Qc[i][f];
        float dp = 0.f;
        int n0 = wave * 36;
        for (int n = n0; n < n0 + 36; ++n) {
            float ph;
            if (n == 0) ph = 1.f;
            else if (n < 17) ph = qr[n - 1] * 0.5f;
            else if (n < 273) { int m = n - 17; ph = qr[m >> 4] * qr[m & 15] * C2; }
            else ph = 0.f;
            Pq[i][n] = f2bf(ph);
            dp += ph * zl[n];
        }
        dpart[wave][i] = dp;
    }

    // causal quadratic scores + per-quarter row sums
    #pragma unroll
    for (int mi = 0; mi < 2; ++mi) {
        float rs[4];
        #pragma unroll
        for (int r = 0; r < 4; ++r) {
            int i = wm * 32 + mi * 16 + quad * 4 + r;
            int j = wn * 16 + lr;
            float u = accS[mi][r];
            float sc = (j <= i) ? (1.f + 0.25f * u + u * u * (1.f / 32.f)) : 0.f;
            rs[r] = sc;
            Pq[i][288 + j] = f2bf(sc);
        }
        #pragma unroll
        for (int r = 0; r < 4; ++r) {
            float v = rs[r];
            v += __shfl_xor(v, 1);
            v += __shfl_xor(v, 2);
            v += __shfl_xor(v, 4);
            v += __shfl_xor(v, 8);
            if (lr == 0) dpart[8 + wn][wm * 32 + mi * 16 + quad * 4 + r] = v;
        }
    }
    __syncthreads();

    // final GEMM: y_tile = Pq(64x352) @ [S_T | V]^T, wave tile 32x16
    f32x4 acc[2] = {{0.f,0.f,0.f,0.f},{0.f,0.f,0.f,0.f}};
    __builtin_amdgcn_s_setprio(1);
    #pragma unroll
    for (int ks = 0; ks < 11; ++ks) {
        short8 bfr = (ks < 9)
            ? sfr[ks]
            : *(const short8*)&Vt[wn * 16 + lr][(ks - 9) * 32 + quad * 8];
        #pragma unroll
        for (int mi = 0; mi < 2; ++mi) {
            short8 af = *(const short8*)&Pq[wm * 32 + mi * 16 + lr][ks * 32 + quad * 8];
            acc[mi] = __builtin_amdgcn_mfma_f32_16x16x32_bf16(af, bfr, acc[mi], 0, 0, 0);
        }
    }
    __builtin_amdgcn_s_setprio(0);

    #pragma unroll
    for (int mi = 0; mi < 2; ++mi)
        #pragma unroll
        for (int r = 0; r < 4; ++r) {
            int i = wm * 32 + mi * 16 + quad * 4 + r;
            float den = 1e-12f;
            #pragma unroll
            for (int w = 0; w < 12; ++w) den += dpart[w][i];
            float rden = 1.f / den;
            y[(size_t)(c * 64 + i) * 768 + h * 64 + wn * 16 + lr] = f2bf(acc[mi][r] * rden);
        }
}

extern "C" void kernel_launch(void* const* d_in, const int* in_sizes, int n_in,
                              void* d_out, int out_size, void* d_ws, size_t ws_size,
                              hipStream_t stream) {
    const float* hs = (const float*)d_in[0];
    const float* Wq = (const float*)d_in[1];
    const float* Wk = (const float*)d_in[2];
    const float* Wv = (const float*)d_in[3];
    const float* Wo = (const float*)d_in[4];
    float* out = (float*)d_out;
    float* ws  = (float*)d_ws;

    // Workspace layout (float offsets; all 16B-aligned):
    float*          qkv  = ws;                                   // 1024x1152 fp32 (Q,K cols only)
    unsigned short* qkvh = (unsigned short*)(ws + 1179648);      // 1024x1152 bf16
    unsigned short* yb   = (unsigned short*)(ws + 1769472);      // 1024x768  bf16
    unsigned short* St   = (unsigned short*)(ws + 2162688);      // 12*16*64*288 bf16
    float*          zb   = ws + 3932160;                         // 12*16*273 fp32
    unsigned short* Hh   = (unsigned short*)(ws + 3984576);      // 1024x768 bf16
    unsigned short* Wqh  = (unsigned short*)(ws + 4377792);      // 768x192 bf16
    unsigned short* Wkh  = (unsigned short*)(ws + 4451520);      // 768x192 bf16
    unsigned short* Wvh  = (unsigned short*)(ws + 4525248);      // 768x768 bf16
    unsigned short* Woh  = (unsigned short*)(ws + 4820160);      // 768x768 bf16

    cvt_prep     <<<552, 512, 0, stream>>>(hs, Wq, Wk, Wv, Wo, Hh, Wqh, Wkh, Wvh, Woh);
    gemm_qkv_mfma<<<dim3(18, 16), 512, 0, stream>>>(Hh, Wqh, Wkh, Wvh, qkv, qkvh);
    chunk_state_k<<<dim3(16, 12), 512, 0, stream>>>(qkv, qkvh, St, zb);
    scan_state_k <<<121, 256, 0, stream>>>(St, zb);
    chunk_out_k  <<<dim3(16, 12), 512, 0, stream>>>(qkv, qkvh, St, zb, yb);
    gemm_wo_mfma <<<dim3(12, 16), 512, 0, stream>>>(yb, Woh, out);
}